// Round 1
// baseline (67.466 us; speedup 1.0000x reference)
//
#include <hip/hip_runtime.h>
#include <utility>

#define BATCH 32768
#define NPHI 35

// ---------- compile-time combinatorics ----------
constexpr int choose2(int n){ return (n*(n-1))/2; }

// lexicographic index of sorted triple (a<b<c) among combinations(7,3)
constexpr int tri_id_sorted(int a,int b,int c){
  int id=0;
  for(int x=0;x<a;++x) id += choose2(6-x);
  for(int y=a+1;y<b;++y) id += (6-y);
  id += (c-b-1);
  return id;
}

constexpr int tri_id3(int a,int b,int c){
  int x=a,y=b,z=c;
  if (x>y){int t=x;x=y;y=t;}
  if (y>z){int t=y;y=z;z=t;}
  if (x>y){int t=x;x=y;y=t;}
  return tri_id_sorted(x,y,z);
}

// parity sign of (a,b,c) w.r.t. sorted order (values distinct)
constexpr int sgn3(int a,int b,int c){
  int inv = (a>b)+(a>c)+(b>c);
  return (inv&1)? -1 : 1;
}

// upper-triangle index for 7x7 symmetric, i<=j
constexpr int UT(int i,int j){
  return i*7 - (i*(i-1))/2 + (j-i);
}

// pair index for k<l among C(7,2)=21
constexpr int PAIR(int k,int l){
  return k*7 - (k*(k+1))/2 + (l - k - 1);
}

// ---------- the straight-line "program": 1470 fma-like ops ----------
struct Prog {
  int n;
  unsigned char kind[1472];
  unsigned char init[1472];   // 1 = first write to dst (use mul, not fma)
  short         dst [1472];
  unsigned char a   [1472];
  short         b   [1472];
  signed char   s   [1472];
};

constexpr Prog build_prog(){
  Prog P{}; P.n=0;
  bool uinit[28]={};
  for(int k=0;k<7;++k) for(int l=k+1;l<7;++l){
    const int kl = PAIR(k,l);
    bool tinit[7]={};
    // ---- T phase for this (k,l)
    for(int m=0;m<7;++m) for(int n2=m+1;n2<7;++n2){
      if(m==k||m==l||n2==k||n2==l) continue;
      int comp[3]={0,0,0}; int cn=0;
      for(int x=0;x<7;++x) if(x!=k&&x!=l&&x!=m&&x!=n2){ comp[cn]=x; ++cn; }
      int perm[7]={k,l,m,n2,comp[0],comp[1],comp[2]};
      int invc=0;
      for(int i=0;i<7;++i) for(int j=i+1;j<7;++j) if(perm[i]>perm[j]) ++invc;
      const int es=(invc&1)? -1 : 1;
      const int tcomp=tri_id_sorted(comp[0],comp[1],comp[2]);
      for(int j=0;j<7;++j){
        if(j==m||j==n2) continue;
        P.kind[P.n]=0;
        P.init[P.n]=tinit[j]?0:1; tinit[j]=true;
        P.dst [P.n]=(short)(kl*7+j);
        P.a   [P.n]=(unsigned char)tcomp;
        P.b   [P.n]=(short)tri_id3(j,m,n2);
        P.s   [P.n]=(signed char)(es*sgn3(j,m,n2));
        ++P.n;
      }
    }
    // ---- B phase for this (k,l)
    for(int i=0;i<7;++i){
      if(i==k||i==l) continue;
      for(int j=i;j<7;++j){
        P.kind[P.n]=1;
        P.init[P.n]=uinit[UT(i,j)]?0:1; uinit[UT(i,j)]=true;
        P.dst [P.n]=(short)UT(i,j);
        P.a   [P.n]=(unsigned char)tri_id3(i,k,l);
        P.b   [P.n]=(short)(kl*7+j);
        P.s   [P.n]=(signed char)sgn3(i,k,l);
        ++P.n;
      }
    }
  }
  return P;
}

static constexpr Prog PROG = build_prog();
static_assert(PROG.n == 1470, "program size unexpected");

// ---------- guaranteed-constant-index execution via fold expression ----------
template<int Q>
__device__ __forceinline__ void step(float (&T)[147], float (&U)[28],
                                     const float (&ph)[NPHI]){
  constexpr int  d = PROG.dst[Q];
  constexpr int  a = PROG.a[Q];
  constexpr int  b = PROG.b[Q];
  constexpr bool neg  = (PROG.s[Q] < 0);
  constexpr bool init = (PROG.init[Q] != 0);
  if constexpr (PROG.kind[Q] == 0){
    const float x = neg ? -ph[a] : ph[a];
    if constexpr (init) T[d] = x * ph[b];
    else                T[d] = fmaf(x, ph[b], T[d]);
  } else {
    const float x = neg ? -ph[a] : ph[a];
    if constexpr (init) U[d] = x * T[b];
    else                U[d] = fmaf(x, T[b], U[d]);
  }
}

template<int... Q>
__device__ __forceinline__ void run_prog(float (&T)[147], float (&U)[28],
                                         const float (&ph)[NPHI],
                                         std::integer_sequence<int, Q...>){
  (step<Q>(T, U, ph), ...);
}

// ---------- round-robin (Brent-Luk) rotation schedule ----------
// Round r pairs: {i,j}, i<j, (i+j) % 7 == r  → 3 disjoint pairs per round,
// 7 rounds cover all 21 pairs exactly once. Disjoint planes ⇒ the three
// rotation-parameter chains in a round are mutually independent (3-way ILP).
constexpr int RP[7][3][2] = {
  {{1,6},{2,5},{3,4}},   // r=0 (0 rests)
  {{0,1},{2,6},{3,5}},   // r=1 (4 rests)
  {{0,2},{3,6},{4,5}},   // r=2 (1 rests)
  {{0,3},{1,2},{4,6}},   // r=3 (5 rests)
  {{0,4},{1,3},{5,6}},   // r=4 (2 rests)
  {{0,5},{1,4},{2,3}},   // r=5 (6 rests)
  {{0,6},{1,5},{2,4}},   // r=6 (3 rests)
};

// ---------- kernel ----------
__global__ __launch_bounds__(64,1)
void PositivityConstraint_89086211654295_kernel(const float* __restrict__ phi,
                                                float* __restrict__ out){
  const int gid = blockIdx.x*64 + threadIdx.x;   // BATCH == 512*64 exactly

  const float* __restrict__ p = phi + (size_t)gid * NPHI;
  float ph[NPHI];
  #pragma unroll
  for (int i=0;i<NPHI;++i) ph[i] = p[i];

  float T[147];   // scalarized by constant indexing; short live ranges
  float U[28];
  run_prog(T, U, ph, std::make_integer_sequence<int, PROG.n>{});

  float A[28];
  #pragma unroll
  for (int i=0;i<28;++i) A[i] = U[i]*(1.0f/6.0f);

  // Parallel-ordered cyclic Jacobi, 6 sweeps.
  // Per rotation: half-angle form — w=rsq(x²+y²), u=|x|w=cos2θ,
  //   c=√(½+½u), |s|=|y|·rsq(2·ss·(1+u))   (cancellation-free),
  //   s = −sgn(x)sgn(y)|s|, diag via m1 = ½u·x − cs·y (exact consistency).
  // 3 trans (was 4), chain ~65 cy (was ~100), 3 chains in flight per round.
  #pragma unroll 1
  for (int sweep=0; sweep<6; ++sweep){
    #pragma unroll
    for (int rr=0; rr<7; ++rr){
      float c3[3], s3[3], m3[3], av3[3];
      // --- phase 1: rotation params for the 3 disjoint pairs (independent) ---
      #pragma unroll
      for (int kp=0; kp<3; ++kp){
        const int p1 = RP[rr][kp][0], q1 = RP[rr][kp][1];
        const float app = A[UT(p1,p1)], aqq = A[UT(q1,q1)], apq = A[UT(p1,q1)];
        const float x   = app - aqq;
        const float y   = apq + apq;
        const float ax  = fabsf(x) + 1e-18f;          // guard: x=y=0 → (c,s)=(1,0)
        const float ss  = fmaf(ax, ax, y*y);
        const float w   = __builtin_amdgcn_rsqf(ss);  // 1/r
        const float u   = ax * w;                     // cos2θ ∈ (0,1]
        const float c   = __builtin_amdgcn_sqrtf(fmaf(0.5f, u, 0.5f));
        const float ss2 = ss + ss;
        const float dd2 = fmaf(ss2, u, ss2);          // 2·r·(r+|x|)
        const float sm  = fabsf(y) * __builtin_amdgcn_rsqf(dd2);  // |sinθ|
        const unsigned sb = (__float_as_uint(x) ^ __float_as_uint(y)) & 0x80000000u;
        const float s1  = sb ? sm : -sm;              // s = −sgn(xy)|s|
        const float cs  = c * s1;
        const float m1  = fmaf(0.5f*u, x, -(cs*y));   // app' − avg
        c3[kp]=c; s3[kp]=s1; m3[kp]=m1; av3[kp]=0.5f*(app+aqq);
      }
      // --- phase 2: apply the 3 rotations (cross entries compose in order) ---
      #pragma unroll
      for (int kp=0; kp<3; ++kp){
        const int p1 = RP[rr][kp][0], q1 = RP[rr][kp][1];
        const float c = c3[kp], s1 = s3[kp];
        A[UT(p1,p1)] = av3[kp] + m3[kp];
        A[UT(q1,q1)] = av3[kp] - m3[kp];
        A[UT(p1,q1)] = 0.0f;
        #pragma unroll
        for (int r2=0; r2<7; ++r2){
          if (r2==p1 || r2==q1) continue;
          const int irp = (r2<p1)? UT(r2,p1) : UT(p1,r2);
          const int irq = (r2<q1)? UT(r2,q1) : UT(q1,r2);
          const float arp = A[irp], arq = A[irq];
          A[irp] = fmaf(c,  arp, -(s1*arq));
          A[irq] = fmaf(s1, arp,   c*arq);
        }
      }
    }
  }

  // det(B) = product of eigenvalues; eig(g) = eig(B) / (|det|+1e-12)^(1/9)
  float det = 1.0f;
  #pragma unroll
  for (int i=0;i<7;++i) det *= A[UT(i,i)];
  const float ad = fabsf(det) + 1e-12f;
  const float scale = __builtin_amdgcn_exp2f(__builtin_amdgcn_logf(ad) * (1.0f/9.0f));
  const float inv = __builtin_amdgcn_rcpf(scale);

  float sum = 0.0f;
  #pragma unroll
  for (int i=0;i<7;++i){
    const float ev = A[UT(i,i)]*inv;
    const float r = 1e-6f - ev;
    sum += fmaxf(r, 0.0f);
  }
  out[gid] = sum;
}

// ---------- launch ----------
extern "C" void kernel_launch(void* const* d_in, const int* in_sizes, int n_in,
                              void* d_out, int out_size, void* d_ws, size_t ws_size,
                              hipStream_t stream) {
  const float* phi = (const float*)d_in[0];
  float* out = (float*)d_out;
  (void)in_sizes; (void)n_in; (void)out_size; (void)d_ws; (void)ws_size;
  hipLaunchKernelGGL(PositivityConstraint_89086211654295_kernel,
                     dim3(BATCH/64), dim3(64), 0, stream, phi, out);
}

// Round 2
// 66.519 us; speedup vs baseline: 1.0142x; 1.0142x over previous
//
#include <hip/hip_runtime.h>
#include <utility>

#define BATCH 32768
#define NPHI 35

typedef float v2f __attribute__((ext_vector_type(2)));

// ---------- compile-time combinatorics ----------
constexpr int choose2(int n){ return (n*(n-1))/2; }

// lexicographic index of sorted triple (a<b<c) among combinations(7,3)
constexpr int tri_id_sorted(int a,int b,int c){
  int id=0;
  for(int x=0;x<a;++x) id += choose2(6-x);
  for(int y=a+1;y<b;++y) id += (6-y);
  id += (c-b-1);
  return id;
}

constexpr int tri_id3(int a,int b,int c){
  int x=a,y=b,z=c;
  if (x>y){int t=x;x=y;y=t;}
  if (y>z){int t=y;y=z;z=t;}
  if (x>y){int t=x;x=y;y=t;}
  return tri_id_sorted(x,y,z);
}

// parity sign of (a,b,c) w.r.t. sorted order (values distinct)
constexpr int sgn3(int a,int b,int c){
  int inv = (a>b)+(a>c)+(b>c);
  return (inv&1)? -1 : 1;
}

// upper-triangle index for 7x7 symmetric, i<=j
constexpr int UT(int i,int j){
  return i*7 - (i*(i-1))/2 + (j-i);
}

// pair index for k<l among C(7,2)=21
constexpr int PAIR(int k,int l){
  return k*7 - (k*(k+1))/2 + (l - k - 1);
}

// ---------- the straight-line "program": 1470 fma-like ops ----------
struct Prog {
  int n;
  unsigned char kind[1472];
  unsigned char init[1472];   // 1 = first write to dst (use mul, not fma)
  short         dst [1472];
  unsigned char a   [1472];
  short         b   [1472];
  signed char   s   [1472];
};

constexpr Prog build_prog(){
  Prog P{}; P.n=0;
  bool uinit[28]={};
  for(int k=0;k<7;++k) for(int l=k+1;l<7;++l){
    const int kl = PAIR(k,l);
    bool tinit[7]={};
    // ---- T phase for this (k,l)
    for(int m=0;m<7;++m) for(int n2=m+1;n2<7;++n2){
      if(m==k||m==l||n2==k||n2==l) continue;
      int comp[3]={0,0,0}; int cn=0;
      for(int x=0;x<7;++x) if(x!=k&&x!=l&&x!=m&&x!=n2){ comp[cn]=x; ++cn; }
      int perm[7]={k,l,m,n2,comp[0],comp[1],comp[2]};
      int invc=0;
      for(int i=0;i<7;++i) for(int j=i+1;j<7;++j) if(perm[i]>perm[j]) ++invc;
      const int es=(invc&1)? -1 : 1;
      const int tcomp=tri_id_sorted(comp[0],comp[1],comp[2]);
      for(int j=0;j<7;++j){
        if(j==m||j==n2) continue;
        P.kind[P.n]=0;
        P.init[P.n]=tinit[j]?0:1; tinit[j]=true;
        P.dst [P.n]=(short)(kl*7+j);
        P.a   [P.n]=(unsigned char)tcomp;
        P.b   [P.n]=(short)tri_id3(j,m,n2);
        P.s   [P.n]=(signed char)(es*sgn3(j,m,n2));
        ++P.n;
      }
    }
    // ---- B phase for this (k,l)
    for(int i=0;i<7;++i){
      if(i==k||i==l) continue;
      for(int j=i;j<7;++j){
        P.kind[P.n]=1;
        P.init[P.n]=uinit[UT(i,j)]?0:1; uinit[UT(i,j)]=true;
        P.dst [P.n]=(short)UT(i,j);
        P.a   [P.n]=(unsigned char)tri_id3(i,k,l);
        P.b   [P.n]=(short)(kl*7+j);
        P.s   [P.n]=(signed char)sgn3(i,k,l);
        ++P.n;
      }
    }
  }
  return P;
}

static constexpr Prog PROG = build_prog();
static_assert(PROG.n == 1470, "program size unexpected");

// ---------- guaranteed-constant-index execution via fold expression ----------
template<int Q>
__device__ __forceinline__ void step(float (&T)[147], float (&U)[28],
                                     const float (&ph)[NPHI]){
  constexpr int  d = PROG.dst[Q];
  constexpr int  a = PROG.a[Q];
  constexpr int  b = PROG.b[Q];
  constexpr bool neg  = (PROG.s[Q] < 0);
  constexpr bool init = (PROG.init[Q] != 0);
  if constexpr (PROG.kind[Q] == 0){
    const float x = neg ? -ph[a] : ph[a];
    if constexpr (init) T[d] = x * ph[b];
    else                T[d] = fmaf(x, ph[b], T[d]);
  } else {
    const float x = neg ? -ph[a] : ph[a];
    if constexpr (init) U[d] = x * T[b];
    else                U[d] = fmaf(x, T[b], U[d]);
  }
}

template<int... Q>
__device__ __forceinline__ void run_prog(float (&T)[147], float (&U)[28],
                                         const float (&ph)[NPHI],
                                         std::integer_sequence<int, Q...>){
  (step<Q>(T, U, ph), ...);
}

// ---------- kernel ----------
__global__ __launch_bounds__(64,1)
void PositivityConstraint_89086211654295_kernel(const float* __restrict__ phi,
                                                float* __restrict__ out){
  const int gid = blockIdx.x*64 + threadIdx.x;   // BATCH == 512*64 exactly

  const float* __restrict__ p = phi + (size_t)gid * NPHI;
  float ph[NPHI];
  // vectorized input: 8 x dwordx4 + 3 x dword (AMD global loads need only
  // 4B alignment for dwordx4; base is 4B-aligned for every gid)
  {
    const float4* __restrict__ p4 = reinterpret_cast<const float4*>(p);
    #pragma unroll
    for (int k=0;k<8;++k){
      const float4 v = p4[k];
      ph[4*k+0]=v.x; ph[4*k+1]=v.y; ph[4*k+2]=v.z; ph[4*k+3]=v.w;
    }
    ph[32]=p[32]; ph[33]=p[33]; ph[34]=p[34];
  }

  float T[147];   // scalarized by constant indexing; short live ranges
  float U[28];
  run_prog(T, U, ph, std::make_integer_sequence<int, PROG.n>{});

  float A[28];
  #pragma unroll
  for (int i=0;i<28;++i) A[i] = U[i]*(1.0f/6.0f);

  // Cyclic Jacobi (round-0 ordering + math: known-good accuracy), 6 sweeps,
  // with a wave-uniform adaptive skip: once ALL 64 lanes have
  // |apq| <= 1e-7*(|app|+|aqq|), the rotation is ~identity (eigenvalue
  // perturbation <= ~1e-7*||A|| — below fp32 noise) and is skipped.
  // Late sweeps become cheap scans; the 6-sweep accuracy envelope is kept.
  // Row updates use packed f32 (v_pk_mul/v_pk_fma on gfx950).
  #pragma unroll 1
  for (int sweep=0; sweep<6; ++sweep){
    #pragma unroll
    for (int p1=0;p1<7;++p1){
      #pragma unroll
      for (int q1=p1+1;q1<7;++q1){
        const float apq = A[UT(p1,q1)];
        const float app = A[UT(p1,p1)];
        const float aqq = A[UT(q1,q1)];
        if (__any(fabsf(apq) > 1e-7f*(fabsf(app)+fabsf(aqq)))) {
          float d = 2.0f*apq;
          d = d + ((d >= 0.0f)? 1e-30f : -1e-30f);     // avoid 0/0
          const float tau = (aqq - app) * __builtin_amdgcn_rcpf(d);
          float t = __builtin_amdgcn_rcpf(
                      fabsf(tau) + __builtin_amdgcn_sqrtf(fmaf(tau,tau,1.0f)));
          t = (tau >= 0.0f)? t : -t;
          const float c = __builtin_amdgcn_rsqf(fmaf(t,t,1.0f));
          const float s = t*c;
          A[UT(p1,p1)] = fmaf(-t, apq, app);
          A[UT(q1,q1)] = fmaf( t, apq, aqq);
          A[UT(p1,q1)] = 0.0f;
          const v2f cs  = {  c, s };
          const v2f msc = { -s, c };
          #pragma unroll
          for (int r=0;r<7;++r){
            if (r==p1 || r==q1) continue;
            const int irp = (r<p1)? UT(r,p1) : UT(p1,r);
            const int irq = (r<q1)? UT(r,q1) : UT(q1,r);
            const v2f arp2 = { A[irp], A[irp] };
            const v2f arq2 = { A[irq], A[irq] };
            // {c*arp - s*arq, s*arp + c*arq} in two packed ops
            const v2f res = __builtin_elementwise_fma(cs, arp2, msc*arq2);
            A[irp] = res.x;
            A[irq] = res.y;
          }
        }
      }
    }
  }

  // det(B) = product of eigenvalues; eig(g) = eig(B) / (|det|+1e-12)^(1/9)
  float det = 1.0f;
  #pragma unroll
  for (int i=0;i<7;++i) det *= A[UT(i,i)];
  const float ad = fabsf(det) + 1e-12f;
  const float scale = __builtin_amdgcn_exp2f(__builtin_amdgcn_logf(ad) * (1.0f/9.0f));
  const float inv = __builtin_amdgcn_rcpf(scale);

  float sum = 0.0f;
  #pragma unroll
  for (int i=0;i<7;++i){
    const float ev = A[UT(i,i)]*inv;
    const float r = 1e-6f - ev;
    sum += fmaxf(r, 0.0f);
  }
  out[gid] = sum;
}

// ---------- launch ----------
extern "C" void kernel_launch(void* const* d_in, const int* in_sizes, int n_in,
                              void* d_out, int out_size, void* d_ws, size_t ws_size,
                              hipStream_t stream) {
  const float* phi = (const float*)d_in[0];
  float* out = (float*)d_out;
  (void)in_sizes; (void)n_in; (void)out_size; (void)d_ws; (void)ws_size;
  hipLaunchKernelGGL(PositivityConstraint_89086211654295_kernel,
                     dim3(BATCH/64), dim3(64), 0, stream, phi, out);
}

// Round 3
// 62.442 us; speedup vs baseline: 1.0805x; 1.0653x over previous
//
#include <hip/hip_runtime.h>
#include <utility>

#define BATCH 32768
#define NPHI 35

typedef float v2f __attribute__((ext_vector_type(2)));

// ---------- compile-time combinatorics ----------
constexpr int choose2(int n){ return (n*(n-1))/2; }

// lexicographic index of sorted triple (a<b<c) among combinations(7,3)
constexpr int tri_id_sorted(int a,int b,int c){
  int id=0;
  for(int x=0;x<a;++x) id += choose2(6-x);
  for(int y=a+1;y<b;++y) id += (6-y);
  id += (c-b-1);
  return id;
}

constexpr int tri_id3(int a,int b,int c){
  int x=a,y=b,z=c;
  if (x>y){int t=x;x=y;y=t;}
  if (y>z){int t=y;y=z;z=t;}
  if (x>y){int t=x;x=y;y=t;}
  return tri_id_sorted(x,y,z);
}

// parity sign of (a,b,c) w.r.t. sorted order (values distinct)
constexpr int sgn3(int a,int b,int c){
  int inv = (a>b)+(a>c)+(b>c);
  return (inv&1)? -1 : 1;
}

// upper-triangle index for 7x7 symmetric, i<=j
constexpr int UT(int i,int j){
  return i*7 - (i*(i-1))/2 + (j-i);
}

// pair index for k<l among C(7,2)=21
constexpr int PAIR(int k,int l){
  return k*7 - (k*(k+1))/2 + (l - k - 1);
}

// ---------- the straight-line "program": 1470 fma-like ops ----------
struct Prog {
  int n;
  unsigned char kind[1472];
  unsigned char init[1472];   // 1 = first write to dst (use mul, not fma)
  short         dst [1472];
  unsigned char a   [1472];
  short         b   [1472];
  signed char   s   [1472];
};

constexpr Prog build_prog(){
  Prog P{}; P.n=0;
  bool uinit[28]={};
  for(int k=0;k<7;++k) for(int l=k+1;l<7;++l){
    const int kl = PAIR(k,l);
    bool tinit[7]={};
    // ---- T phase for this (k,l)
    for(int m=0;m<7;++m) for(int n2=m+1;n2<7;++n2){
      if(m==k||m==l||n2==k||n2==l) continue;
      int comp[3]={0,0,0}; int cn=0;
      for(int x=0;x<7;++x) if(x!=k&&x!=l&&x!=m&&x!=n2){ comp[cn]=x; ++cn; }
      int perm[7]={k,l,m,n2,comp[0],comp[1],comp[2]};
      int invc=0;
      for(int i=0;i<7;++i) for(int j=i+1;j<7;++j) if(perm[i]>perm[j]) ++invc;
      const int es=(invc&1)? -1 : 1;
      const int tcomp=tri_id_sorted(comp[0],comp[1],comp[2]);
      for(int j=0;j<7;++j){
        if(j==m||j==n2) continue;
        P.kind[P.n]=0;
        P.init[P.n]=tinit[j]?0:1; tinit[j]=true;
        P.dst [P.n]=(short)(kl*7+j);
        P.a   [P.n]=(unsigned char)tcomp;
        P.b   [P.n]=(short)tri_id3(j,m,n2);
        P.s   [P.n]=(signed char)(es*sgn3(j,m,n2));
        ++P.n;
      }
    }
    // ---- B phase for this (k,l)
    for(int i=0;i<7;++i){
      if(i==k||i==l) continue;
      for(int j=i;j<7;++j){
        P.kind[P.n]=1;
        P.init[P.n]=uinit[UT(i,j)]?0:1; uinit[UT(i,j)]=true;
        P.dst [P.n]=(short)UT(i,j);
        P.a   [P.n]=(unsigned char)tri_id3(i,k,l);
        P.b   [P.n]=(short)(kl*7+j);
        P.s   [P.n]=(signed char)sgn3(i,k,l);
        ++P.n;
      }
    }
  }
  return P;
}

static constexpr Prog PROG = build_prog();
static_assert(PROG.n == 1470, "program size unexpected");

// ---------- guaranteed-constant-index execution via fold expression ----------
// sched_barrier(0) at every T-phase/B-phase transition pins the source's
// liveness-bounded interleave (ph[35]+U[28]+T[~7] ≈ 80 live values): the
// pre-RA scheduler cannot hoist T-computations across (k,l) groups, which
// is the suspected spill-inducing pathology at 1 wave/SIMD.
template<int Q>
__device__ __forceinline__ void step(float (&T)[147], float (&U)[28],
                                     const float (&ph)[NPHI]){
  if constexpr (Q > 0 && PROG.kind[Q] != PROG.kind[Q-1]) {
    __builtin_amdgcn_sched_barrier(0);
  }
  constexpr int  d = PROG.dst[Q];
  constexpr int  a = PROG.a[Q];
  constexpr int  b = PROG.b[Q];
  constexpr bool neg  = (PROG.s[Q] < 0);
  constexpr bool init = (PROG.init[Q] != 0);
  if constexpr (PROG.kind[Q] == 0){
    const float x = neg ? -ph[a] : ph[a];
    if constexpr (init) T[d] = x * ph[b];
    else                T[d] = fmaf(x, ph[b], T[d]);
  } else {
    const float x = neg ? -ph[a] : ph[a];
    if constexpr (init) U[d] = x * T[b];
    else                U[d] = fmaf(x, T[b], U[d]);
  }
}

template<int... Q>
__device__ __forceinline__ void run_prog(float (&T)[147], float (&U)[28],
                                         const float (&ph)[NPHI],
                                         std::integer_sequence<int, Q...>){
  (step<Q>(T, U, ph), ...);
}

// one Jacobi rotation; GUARD is compile-time: when set, the rotation is
// skipped if ALL 64 lanes have |apq| <= 1e-6*(|app|+|aqq|) (skipping such a
// rotation perturbs eigenvalues by <= |apq| — Weyl — i.e. ~1e-6*scale).
#define ROT_BODY(p1, q1, GUARD)                                               \
  {                                                                           \
    const float apq = A[UT(p1,q1)];                                           \
    const float app = A[UT(p1,p1)];                                           \
    const float aqq = A[UT(q1,q1)];                                           \
    bool doit = true;                                                         \
    if (GUARD) doit = __any(fabsf(apq) > 1e-6f*(fabsf(app)+fabsf(aqq)));      \
    if (doit) {                                                               \
      float d = 2.0f*apq;                                                     \
      d = d + ((d >= 0.0f)? 1e-30f : -1e-30f);                                \
      const float tau = (aqq - app) * __builtin_amdgcn_rcpf(d);               \
      float t = __builtin_amdgcn_rcpf(                                        \
                  fabsf(tau) + __builtin_amdgcn_sqrtf(fmaf(tau,tau,1.0f)));   \
      t = (tau >= 0.0f)? t : -t;                                              \
      const float c = __builtin_amdgcn_rsqf(fmaf(t,t,1.0f));                  \
      const float s = t*c;                                                    \
      A[UT(p1,p1)] = fmaf(-t, apq, app);                                      \
      A[UT(q1,q1)] = fmaf( t, apq, aqq);                                      \
      A[UT(p1,q1)] = 0.0f;                                                    \
      const v2f cs  = {  c, s };                                              \
      const v2f msc = { -s, c };                                              \
      _Pragma("unroll")                                                       \
      for (int r=0;r<7;++r){                                                  \
        if (r==p1 || r==q1) continue;                                         \
        const int irp = (r<p1)? UT(r,p1) : UT(p1,r);                          \
        const int irq = (r<q1)? UT(r,q1) : UT(q1,r);                          \
        const v2f arp2 = { A[irp], A[irp] };                                  \
        const v2f arq2 = { A[irq], A[irq] };                                  \
        const v2f res = __builtin_elementwise_fma(cs, arp2, msc*arq2);        \
        A[irp] = res.x;                                                       \
        A[irq] = res.y;                                                       \
      }                                                                       \
    }                                                                         \
  }

// ---------- kernel ----------
__global__ __launch_bounds__(64,1)
void PositivityConstraint_89086211654295_kernel(const float* __restrict__ phi,
                                                float* __restrict__ out){
  const int gid = blockIdx.x*64 + threadIdx.x;   // BATCH == 512*64 exactly

  const float* __restrict__ p = phi + (size_t)gid * NPHI;
  float ph[NPHI];
  // vectorized input: 8 x dwordx4 + 3 x dword
  {
    const float4* __restrict__ p4 = reinterpret_cast<const float4*>(p);
    #pragma unroll
    for (int k=0;k<8;++k){
      const float4 v = p4[k];
      ph[4*k+0]=v.x; ph[4*k+1]=v.y; ph[4*k+2]=v.z; ph[4*k+3]=v.w;
    }
    ph[32]=p[32]; ph[33]=p[33]; ph[34]=p[34];
  }

  float T[147];   // scalarized by constant indexing; short live ranges
  float U[28];
  run_prog(T, U, ph, std::make_integer_sequence<int, PROG.n>{});
  __builtin_amdgcn_sched_barrier(0);

  float A[28];
  #pragma unroll
  for (int i=0;i<28;++i) A[i] = U[i]*(1.0f/6.0f);

  // Cyclic Jacobi: 4 full sweeps (quadratic convergence → off-diag ~1e-8
  // after 4), then ONE skip-guarded polish pass (wave-uniform __any guard;
  // converged lanes pay 5 instrs per rotation instead of ~35).
  #pragma unroll 1
  for (int sweep=0; sweep<4; ++sweep){
    #pragma unroll
    for (int p1=0;p1<7;++p1){
      #pragma unroll
      for (int q1=p1+1;q1<7;++q1){
        ROT_BODY(p1, q1, false)
      }
    }
  }
  { // polish pass
    #pragma unroll
    for (int p1=0;p1<7;++p1){
      #pragma unroll
      for (int q1=p1+1;q1<7;++q1){
        ROT_BODY(p1, q1, true)
      }
    }
  }

  // det(B) = product of eigenvalues; eig(g) = eig(B) / (|det|+1e-12)^(1/9)
  float det = 1.0f;
  #pragma unroll
  for (int i=0;i<7;++i) det *= A[UT(i,i)];
  const float ad = fabsf(det) + 1e-12f;
  const float scale = __builtin_amdgcn_exp2f(__builtin_amdgcn_logf(ad) * (1.0f/9.0f));
  const float inv = __builtin_amdgcn_rcpf(scale);

  float sum = 0.0f;
  #pragma unroll
  for (int i=0;i<7;++i){
    const float ev = A[UT(i,i)]*inv;
    const float r = 1e-6f - ev;
    sum += fmaxf(r, 0.0f);
  }
  out[gid] = sum;
}

// ---------- launch ----------
extern "C" void kernel_launch(void* const* d_in, const int* in_sizes, int n_in,
                              void* d_out, int out_size, void* d_ws, size_t ws_size,
                              hipStream_t stream) {
  const float* phi = (const float*)d_in[0];
  float* out = (float*)d_out;
  (void)in_sizes; (void)n_in; (void)out_size; (void)d_ws; (void)ws_size;
  hipLaunchKernelGGL(PositivityConstraint_89086211654295_kernel,
                     dim3(BATCH/64), dim3(64), 0, stream, phi, out);
}